// Round 9
// baseline (226.999 us; speedup 1.0000x reference)
//
#include <hip/hip_runtime.h>
#include <hip/hip_bf16.h>
#include <cstdint>
#include <cstddef>

// Problem constants
#define B_  2
#define T_  2048
#define C_  1024
#define H_  16
#define D_  64
#define NEG_INF_ -1e9f

typedef short bf16x8 __attribute__((ext_vector_type(8)));
typedef float f32x4  __attribute__((ext_vector_type(4)));

__device__ __forceinline__ short f2bf(float f) {
  union { float f; unsigned u; } x; x.f = f;
  unsigned r = (x.u + 0x7fffu + ((x.u >> 16) & 1u)) >> 16;  // RNE
  return (short)r;
}

__device__ __forceinline__ float bf2f(short s) {
  union { float f; unsigned u; } x;
  x.u = ((unsigned)(unsigned short)s) << 16;
  return x.f;
}

__device__ __forceinline__ void gload16(const void* g, void* l) {
  // async global->LDS, 16B per lane; LDS dest = wave-uniform base + lane*16
  __builtin_amdgcn_global_load_lds(
      (const __attribute__((address_space(1))) unsigned int*)g,
      (__attribute__((address_space(3))) unsigned int*)l, 16, 0, 0);
}

// ---------------- fp32 -> bf16 convert (vectorized) ----------------
__global__ __launch_bounds__(256) void cvt_bf16(const float* __restrict__ in,
                                                short* __restrict__ out, int n4) {
  int i = blockIdx.x * 256 + threadIdx.x;
  if (i < n4) {
    float4 v = ((const float4*)in)[i];
    short4 o;
    o.x = f2bf(v.x); o.y = f2bf(v.y); o.z = f2bf(v.z); o.w = f2bf(v.w);
    ((short4*)out)[i] = o;
  }
}

// ---------------- transpose + convert: in[R][C] fp32 -> out[C][R] bf16 ------
__global__ __launch_bounds__(256) void transpose_cvt(const float* __restrict__ in,
                                                     short* __restrict__ out,
                                                     int R, int C) {
  __shared__ float tile[32][33];
  int gx = blockIdx.x * 32, gy = blockIdx.y * 32;
  int tx = threadIdx.x, ty = threadIdx.y;  // (32,8)
#pragma unroll
  for (int i = 0; i < 4; ++i)
    tile[ty + i * 8][tx] = in[(size_t)(gy + ty + i * 8) * C + gx + tx];
  __syncthreads();
#pragma unroll
  for (int i = 0; i < 4; ++i)
    out[(size_t)(gx + ty + i * 8) * R + gy + tx] = f2bf(tile[tx][ty + i * 8]);
}

// ---------------- T5 bias table: bias[h][dist], dist in [0,2048) -----------
__global__ __launch_bounds__(256) void bias_table(const float* __restrict__ rel_table,
                                                  float* __restrict__ btab) {
  int idx = blockIdx.x * 256 + threadIdx.x;  // 16*2048
  if (idx >= H_ * T_) return;
  int dist = idx & (T_ - 1);
  int h = idx >> 11;
  int bucket;
  if (dist < 16) {
    bucket = dist;
  } else {
    float rp = (float)dist;
    int large = 16 + (int)(logf(rp * (1.0f / 16.0f)) * (1.0f / logf(128.0f)) * 16.0f);
    bucket = large < 31 ? large : 31;
  }
  btab[idx] = rel_table[bucket * H_ + h];
}

// ---------------- bf16 GEMM: C[M,N] = A[M,K] * Bt[N,K]^T -------------------
// 128x128 tile, BK=64, 4 waves, 16x16x32 MFMA, global_load_lds(16),
// XOR-swizzled LDS (rows are 128B -> swizzle byte ^= (row&7)<<4).
// MODE 0: scatter epilogue -> q(bf16,*0.125)/k(bf16)/vT(bf16 transposed)
// MODE 1: fp32 out
template <int MODE>
__global__ __launch_bounds__(256) void gemm_bt128(
    const short* __restrict__ A, const short* __restrict__ Bt,
    int M, int N, int K,
    short* __restrict__ q_out, short* __restrict__ k_out,
    short* __restrict__ vT_out, float* __restrict__ f_out) {
  __shared__ alignas(16) short As[128 * 64];
  __shared__ alignas(16) short Bs[128 * 64];
  const int tid = threadIdx.x;
  const int w = tid >> 6, lane = tid & 63;
  const int g = lane >> 4, l16 = lane & 15;
  const int wr = w >> 1, wc = w & 1;
  const int m0 = blockIdx.y * 128, n0 = blockIdx.x * 128;

  const char* Ag = (const char*)(A + (size_t)m0 * K);
  const char* Bg = (const char*)(Bt + (size_t)n0 * K);
  char* AsB = (char*)As;
  char* BsB = (char*)Bs;

  // staging: 1024 16B-chunks per tile, 4 per thread; pre-swizzle source chunk
  int goff[4];
#pragma unroll
  for (int i = 0; i < 4; ++i) {
    int o = i * 256 + tid;
    int row = o >> 3, ch = o & 7;
    goff[i] = row * (K * 2) + ((ch ^ (row & 7)) << 4);
  }

  f32x4 acc[4][4] = {};

  const int nkt = K >> 6;
  for (int kt = 0; kt < nkt; ++kt) {
    __syncthreads();
    const int kbyte = kt << 7;
#pragma unroll
    for (int i = 0; i < 4; ++i)
      gload16(Ag + goff[i] + kbyte, AsB + i * 4096 + w * 1024);
#pragma unroll
    for (int i = 0; i < 4; ++i)
      gload16(Bg + goff[i] + kbyte, BsB + i * 4096 + w * 1024);
    __syncthreads();
#pragma unroll
    for (int kk = 0; kk < 2; ++kk) {
      bf16x8 af[4], bff[4];
#pragma unroll
      for (int m = 0; m < 4; ++m) {
        int r = wr * 64 + m * 16 + l16;
        int off = (r * 128 + kk * 64 + g * 16) ^ ((r & 7) << 4);
        af[m] = *(const bf16x8*)(AsB + off);
      }
#pragma unroll
      for (int n = 0; n < 4; ++n) {
        int c = wc * 64 + n * 16 + l16;
        int off = (c * 128 + kk * 64 + g * 16) ^ ((c & 7) << 4);
        bff[n] = *(const bf16x8*)(BsB + off);
      }
#pragma unroll
      for (int m = 0; m < 4; ++m)
#pragma unroll
        for (int n = 0; n < 4; ++n)
          acc[m][n] = __builtin_amdgcn_mfma_f32_16x16x32_bf16(af[m], bff[n], acc[m][n], 0, 0, 0);
    }
  }

  // epilogue: C/D layout col=lane&15, row=(lane>>4)*4+r
#pragma unroll
  for (int m = 0; m < 4; ++m) {
#pragma unroll
    for (int n = 0; n < 4; ++n) {
      const int colg = n0 + wc * 64 + n * 16 + l16;
#pragma unroll
      for (int r = 0; r < 4; ++r) {
        const int rowg = m0 + wr * 64 + m * 16 + g * 4 + r;
        float v = acc[m][n][r];
        if (MODE == 1) {
          f_out[(size_t)rowg * N + colg] = v;
        } else {
          int part = colg >> 10;
          int within = colg & 1023;
          int h = within >> 6, dd = within & 63;
          int b = rowg >> 11, t = rowg & (T_ - 1);
          size_t bh = (size_t)(b * H_ + h);
          if (part == 0)
            q_out[(bh * T_ + t) * D_ + dd] = f2bf(v * 0.125f);  // fold 1/sqrt(d)
          else if (part == 1)
            k_out[(bh * T_ + t) * D_ + dd] = f2bf(v);
          else
            vT_out[(bh * D_ + dd) * T_ + t] = f2bf(v);  // V transposed
        }
      }
    }
  }
}

// ---------------- flash attention with T5 bias, causal ---------------------
// KV-SPLIT work-balanced pairs: block (j, bh, s) handles q-tiles qlo=j,
// qhi=31-j, processing kv-tiles t = s, s+2, ... (t <= qhi). Each s-part
// emits UNNORMALIZED O (bf16) + per-row (m,l); attn_merge combines.
// -> 1024 blocks x 4 waves = 16 waves/CU (4 blocks/CU at 34.8KB LDS).
// K double-buffered (prefetch t+2); V single-buffered, made safe by a
// mid-iteration counted vmcnt + raw barrier before the first PV of the
// iteration (V loads issued at iteration start, hidden under QK+softmax).
__global__ __launch_bounds__(256) void attn64(
    const short* __restrict__ qb, const short* __restrict__ kb,
    const short* __restrict__ vTb, const float* __restrict__ bias_tab,
    short* __restrict__ o1, short* __restrict__ o2, float* __restrict__ mlb) {
  __shared__ alignas(16) short Ks[2][64 * 64];
  __shared__ alignas(16) short Vs[64 * 64];
  __shared__ alignas(16) short Ps[4][16 * 64];
  __shared__ float biasw[2][2][128];   // [buf][lo/hi][idx]
  const int tid = threadIdx.x;
  const int w = tid >> 6, lane = tid & 63;
  const int g = lane >> 4, l16 = lane & 15;
  const int bh = blockIdx.y;          // b*16 + h
  const int h = bh & (H_ - 1);
  const int b = bh >> 4;
  const int j = blockIdx.x;           // pair index 0..15
  const int s = blockIdx.z;           // kv-split part 0/1
  const int qlo = j, qhi = 31 - j;
  const int q0l = qlo * 64, q0h = qhi * 64;

  const char* kbase = (const char*)(kb + (size_t)bh * T_ * D_);
  const char* vbase = (const char*)(vTb + (size_t)bh * D_ * T_);
  const float* btab = bias_tab + h * T_;

  // Q fragments for both q-tiles (A-operand): lane holds row l16
  bf16x8 qfl[2], qfh[2];
  {
    const short* qrl = qb + ((size_t)bh * T_ + q0l + w * 16 + l16) * D_;
    qfl[0] = *(const bf16x8*)(qrl + g * 8);
    qfl[1] = *(const bf16x8*)(qrl + 32 + g * 8);
    const short* qrh = qb + ((size_t)bh * T_ + q0h + w * 16 + l16) * D_;
    qfh[0] = *(const bf16x8*)(qrh + g * 8);
    qfh[1] = *(const bf16x8*)(qrh + 32 + g * 8);
  }

  f32x4 accl[4] = {}, acch[4] = {};
  float mlo[4], llo[4], mhi[4], lhi[4];
#pragma unroll
  for (int r = 0; r < 4; ++r) { mlo[r] = mhi[r] = -1e30f; llo[r] = lhi[r] = 0.f; }

  char* PsB = (char*)&Ps[w][0];

  int krow[2], kch[2];
#pragma unroll
  for (int i = 0; i < 2; ++i) {
    int o = i * 256 + tid;
    krow[i] = o >> 3;
    kch[i] = (o & 7) ^ (krow[i] & 7);
  }

  auto stageK = [&](int buf, int t) {
    const int kv0 = t * 64;
    char* KsB = (char*)&Ks[buf][0];
#pragma unroll
    for (int i = 0; i < 2; ++i)
      gload16(kbase + (size_t)(kv0 + krow[i]) * 128 + kch[i] * 16,
              KsB + i * 4096 + w * 1024);
  };
  auto stageV = [&](int t) {
    const int kv0 = t * 64;
    char* VsB = (char*)Vs;
#pragma unroll
    for (int i = 0; i < 2; ++i)
      gload16(vbase + (size_t)krow[i] * (T_ * 2) + kv0 * 2 + kch[i] * 16,
              VsB + i * 4096 + w * 1024);
  };
  // bias window for tile t: threads <128 load lo-window entry, >=128 hi-window
  auto biasLoad = [&](int t) -> float {
    int i = tid & 127;
    int q0x = (tid >= 128) ? q0h : q0l;
    int d = q0x - t * 64 - 63 + i;
    return (d >= 0 && d < T_) ? btab[d] : NEG_INF_;
  };

  // one q-tile's compute against the staged kv-tile.
  // dosync: this is the first compute of the iteration -> V-ready sync
  // before PV. drain2: K-prefetch (2 loads, newest) may stay in flight.
  auto computeTile = [&](const char* KsB, const float* bw, const bf16x8* qf,
                         f32x4* acc, float* mrun, float* lrun,
                         bool dosync, bool drain2) {
    // S = Q*K^T
    f32x4 sreg[4];
    __builtin_amdgcn_s_setprio(1);
#pragma unroll
    for (int n = 0; n < 4; ++n) {
      int kvrow = n * 16 + l16;
      int off0 = (kvrow * 128 + g * 16) ^ ((kvrow & 7) << 4);
      int off1 = (kvrow * 128 + 64 + g * 16) ^ ((kvrow & 7) << 4);
      bf16x8 k0 = *(const bf16x8*)(KsB + off0);
      bf16x8 k1 = *(const bf16x8*)(KsB + off1);
      f32x4 z = {};
      z = __builtin_amdgcn_mfma_f32_16x16x32_bf16(qf[0], k0, z, 0, 0, 0);
      z = __builtin_amdgcn_mfma_f32_16x16x32_bf16(qf[1], k1, z, 0, 0, 0);
      sreg[n] = z;
    }
    __builtin_amdgcn_s_setprio(0);

    // bias from LDS window + per-row tile max
    float sv[4][4];
    float tmax[4] = {-1e30f, -1e30f, -1e30f, -1e30f};
#pragma unroll
    for (int n = 0; n < 4; ++n) {
#pragma unroll
      for (int r = 0; r < 4; ++r) {
        int idx = 63 + w * 16 + g * 4 + r - n * 16 - l16;
        float val = sreg[n][r] + bw[idx];
        sv[n][r] = val;
        tmax[r] = fmaxf(tmax[r], val);
      }
    }
#pragma unroll
    for (int r = 0; r < 4; ++r) {
      float v = tmax[r];
      v = fmaxf(v, __shfl_xor(v, 1));
      v = fmaxf(v, __shfl_xor(v, 2));
      v = fmaxf(v, __shfl_xor(v, 4));
      v = fmaxf(v, __shfl_xor(v, 8));
      tmax[r] = v;
    }

    // defer-max: only rescale when some row's max grew past THR=8
    bool nogrow = true;
#pragma unroll
    for (int r = 0; r < 4; ++r) nogrow &= (tmax[r] <= mrun[r] + 8.0f);
    if (!__all(nogrow)) {
#pragma unroll
      for (int r = 0; r < 4; ++r) {
        float mnew = fmaxf(mrun[r], tmax[r]);
        float scale = __expf(mrun[r] - mnew);
        mrun[r] = mnew;
        lrun[r] *= scale;
#pragma unroll
        for (int dn = 0; dn < 4; ++dn) acc[dn][r] *= scale;
      }
    }

    // P = exp(S - m); per-lane partial l; P to wave-private LDS (swizzled)
#pragma unroll
    for (int r = 0; r < 4; ++r) {
      float su = 0.f;
#pragma unroll
      for (int n = 0; n < 4; ++n) {
        float p = __expf(sv[n][r] - mrun[r]);
        su += p;
        int row = g * 4 + r, col = n * 16 + l16;
        int off = (row * 128 + col * 2) ^ ((row & 7) << 4);
        *(short*)(PsB + off) = f2bf(p);
      }
      lrun[r] += su;   // per-lane partial; reduced once in epilogue
    }

    // V-ready sync: wait own V loads (oldest; K prefetch = newest 2 may
    // remain in flight), then block barrier so all waves' V parts landed.
    if (dosync) {
      if (drain2) {
        asm volatile("s_waitcnt vmcnt(2)" ::: "memory");
      } else {
        asm volatile("s_waitcnt vmcnt(0)" ::: "memory");
      }
      __builtin_amdgcn_s_barrier();
      __builtin_amdgcn_sched_barrier(0);
    }

    // O += P*V
    const char* VsB = (const char*)Vs;
    bf16x8 pf[2];
    {
      int o0 = (l16 * 128 + g * 16) ^ ((l16 & 7) << 4);
      int o1 = (l16 * 128 + 64 + g * 16) ^ ((l16 & 7) << 4);
      pf[0] = *(const bf16x8*)(PsB + o0);
      pf[1] = *(const bf16x8*)(PsB + o1);
    }
    __builtin_amdgcn_s_setprio(1);
#pragma unroll
    for (int dn = 0; dn < 4; ++dn) {
      int drow = dn * 16 + l16;
      int o0 = (drow * 128 + g * 16) ^ ((drow & 7) << 4);
      int o1 = (drow * 128 + 64 + g * 16) ^ ((drow & 7) << 4);
      bf16x8 v0 = *(const bf16x8*)(VsB + o0);
      bf16x8 v1 = *(const bf16x8*)(VsB + o1);
      acc[dn] = __builtin_amdgcn_mfma_f32_16x16x32_bf16(pf[0], v0, acc[dn], 0, 0, 0);
      acc[dn] = __builtin_amdgcn_mfma_f32_16x16x32_bf16(pf[1], v1, acc[dn], 0, 0, 0);
    }
    __builtin_amdgcn_s_setprio(0);
  };

  // prologue: K of first tile into buf 0 + its bias window
  stageK(0, s);
  {
    float bv = biasLoad(s);
    biasw[0][tid >> 7][tid & 127] = bv;
  }
  __syncthreads();

  int cur = 0;
  for (int t = s; t <= qhi; t += 2) {
    const int nxt = cur ^ 1;
    const bool hasnext = (t + 2 <= qhi);
    float bvn = 0.f;
    if (hasnext) bvn = biasLoad(t + 2);  // VMEM load issued first (oldest)
    stageV(t);                           // V of current tile (single buffer)
    if (hasnext) stageK(nxt, t + 2);     // K prefetch (newest 2 loads)
    const char* KsB = (const char*)&Ks[cur][0];
    bool first = true;
    if (t <= qlo) {
      computeTile(KsB, &biasw[cur][0][0], qfl, accl, mlo, llo, true, hasnext);
      first = false;
    }
    computeTile(KsB, &biasw[cur][1][0], qfh, acch, mhi, lhi, first, hasnext);
    if (hasnext) biasw[nxt][tid >> 7][tid & 127] = bvn;
    __syncthreads();   // full drain: K(t+2) staged; WAR-protects Vs
    cur = nxt;
  }

  // epilogue: reduce l across l16; write UNNORMALIZED O + per-row (m,l)
  short* dst = (s == 0) ? o1 : o2;
  auto writeO = [&](int q0x, const f32x4* acc, const float* mrun, float* lrun) {
#pragma unroll
    for (int r = 0; r < 4; ++r) {
      float v = lrun[r];
      v += __shfl_xor(v, 1);
      v += __shfl_xor(v, 2);
      v += __shfl_xor(v, 4);
      v += __shfl_xor(v, 8);
      int qg = q0x + w * 16 + g * 4 + r;
      size_t ybase = ((size_t)b * T_ + qg) * C_ + h * D_;
#pragma unroll
      for (int dn = 0; dn < 4; ++dn)
        dst[ybase + dn * 16 + l16] = f2bf(acc[dn][r]);
      if (l16 == 0) {
        int idx = (((b * T_) + qg) * H_ + h) * 4 + s * 2;
        mlb[idx] = mrun[r];
        mlb[idx + 1] = v;
      }
    }
  };
  writeO(q0l, accl, mlo, llo);
  writeO(q0h, acch, mhi, lhi);
}

// ---------------- merge the two kv-split partials --------------------------
// y = (w0*O0 + w1*O1) / (w0*l0 + w1*l1), w_s = exp(m_s - max(m0,m1)).
// One thread per 8 output elems (16B). In-place on o1 (=yb).
__global__ __launch_bounds__(256) void attn_merge(
    short* __restrict__ o1, const short* __restrict__ o2,
    const float* __restrict__ mlb) {
  int i = blockIdx.x * 256 + threadIdx.x;   // 524288 total
  int row = i >> 7;                          // b*T + t
  int h = (i & 127) >> 3;
  float4 q = ((const float4*)mlb)[row * H_ + h];  // (m0,l0,m1,l1)
  float m = fmaxf(q.x, q.z);
  float w0 = __expf(q.x - m), w1 = __expf(q.z - m);
  float inv = 1.0f / (w0 * q.y + w1 * q.w);
  bf16x8 a = ((const bf16x8*)o1)[i];
  bf16x8 bb = ((const bf16x8*)o2)[i];
  bf16x8 o;
#pragma unroll
  for (int e = 0; e < 8; ++e)
    o[e] = f2bf((w0 * bf2f(a[e]) + w1 * bf2f(bb[e])) * inv);
  ((bf16x8*)o1)[i] = o;
}

// ---------------------------------------------------------------------------
extern "C" void kernel_launch(void* const* d_in, const int* in_sizes, int n_in,
                              void* d_out, int out_size, void* d_ws, size_t ws_size,
                              hipStream_t stream) {
  const float* x = (const float*)d_in[0];         // [2,2048,1024]
  const float* w_qkv = (const float*)d_in[1];     // [1024,3072]
  const float* w_proj = (const float*)d_in[2];    // [1024,1024]
  const float* rel_table = (const float*)d_in[3]; // [32,16]
  float* out = (float*)d_out;                     // [2,2048,1024]

  const size_t MB = 1024 * 1024;
  char* ws = (char*)d_ws;
  short* xb     = (short*)(ws);             // 8 MB  [4096,1024] bf16 (dead after gemm1)
  short* wqkvT  = (short*)(ws + 8 * MB);    // 6 MB  [3072,1024] bf16 (dead after gemm1)
  short* wprojT = (short*)(ws + 14 * MB);   // 2 MB  [1024,1024] bf16
  short* qb     = (short*)(ws + 16 * MB);   // 8 MB  [B,H,T,64] bf16 (pre-scaled)
  short* kbuf   = (short*)(ws + 24 * MB);   // 8 MB  [B,H,T,64] bf16
  short* vT     = (short*)(ws + 32 * MB);   // 8 MB  [B,H,64,T] bf16
  short* yb     = (short*)(ws + 40 * MB);   // 8 MB  [4096,1024] bf16 (attn part 0 + merged)
  float* btab   = (float*)(ws + 48 * MB);   // 128 KB [16,2048] fp32
  // overlays (regions dead after gemm1):
  short* o2b    = (short*)(ws);             // 8 MB  attn part-1 O (over xb)
  float* mlb    = (float*)(ws + 9 * MB);    // 1 MB  [B,T,H,4] (m0,l0,m1,l1)

  // 1. conversions
  cvt_bf16<<<4096, 256, 0, stream>>>(x, xb, (B_ * T_ * C_) / 4);
  dim3 tb(32, 8);
  transpose_cvt<<<dim3(96, 32), tb, 0, stream>>>(w_qkv, wqkvT, 1024, 3072);
  transpose_cvt<<<dim3(32, 32), tb, 0, stream>>>(w_proj, wprojT, 1024, 1024);
  bias_table<<<128, 256, 0, stream>>>(rel_table, btab);

  // 2. qkv = x @ w_qkv  (scatter to q/k/vT)
  gemm_bt128<0><<<dim3(24, 32), 256, 0, stream>>>(xb, wqkvT, 4096, 3072, 1024,
                                                  qb, kbuf, vT, nullptr);
  // 3. attention (work-balanced pairs x kv-split) + merge
  attn64<<<dim3(16, 32, 2), 256, 0, stream>>>(qb, kbuf, vT, btab, yb, o2b, mlb);
  attn_merge<<<2048, 256, 0, stream>>>(yb, o2b, mlb);

  // 4. out = y @ w_proj
  gemm_bt128<1><<<dim3(8, 32), 256, 0, stream>>>(yb, wprojT, 4096, 1024, 1024,
                                                 nullptr, nullptr, nullptr, out);
}

// Round 10
// 220.850 us; speedup vs baseline: 1.0278x; 1.0278x over previous
//
#include <hip/hip_runtime.h>
#include <hip/hip_bf16.h>
#include <cstdint>
#include <cstddef>

// Problem constants
#define B_  2
#define T_  2048
#define C_  1024
#define H_  16
#define D_  64
#define NEG_INF_ -1e9f
#define LOG2E_ 1.44269504f

typedef short bf16x8 __attribute__((ext_vector_type(8)));
typedef float f32x4  __attribute__((ext_vector_type(4)));

__device__ __forceinline__ short f2bf(float f) {
  union { float f; unsigned u; } x; x.f = f;
  unsigned r = (x.u + 0x7fffu + ((x.u >> 16) & 1u)) >> 16;  // RNE
  return (short)r;
}

__device__ __forceinline__ float bf2f(short s) {
  union { float f; unsigned u; } x;
  x.u = ((unsigned)(unsigned short)s) << 16;
  return x.f;
}

__device__ __forceinline__ void gload16(const void* g, void* l) {
  // async global->LDS, 16B per lane; LDS dest = wave-uniform base + lane*16
  __builtin_amdgcn_global_load_lds(
      (const __attribute__((address_space(1))) unsigned int*)g,
      (__attribute__((address_space(3))) unsigned int*)l, 16, 0, 0);
}

// ---------------- fp32 -> bf16 convert (vectorized) ----------------
__global__ __launch_bounds__(256) void cvt_bf16(const float* __restrict__ in,
                                                short* __restrict__ out, int n4) {
  int i = blockIdx.x * 256 + threadIdx.x;
  if (i < n4) {
    float4 v = ((const float4*)in)[i];
    short4 o;
    o.x = f2bf(v.x); o.y = f2bf(v.y); o.z = f2bf(v.z); o.w = f2bf(v.w);
    ((short4*)out)[i] = o;
  }
}

// ---------------- transpose + convert: in[R][C] fp32 -> out[C][R] bf16 ------
__global__ __launch_bounds__(256) void transpose_cvt(const float* __restrict__ in,
                                                     short* __restrict__ out,
                                                     int R, int C) {
  __shared__ float tile[32][33];
  int gx = blockIdx.x * 32, gy = blockIdx.y * 32;
  int tx = threadIdx.x, ty = threadIdx.y;  // (32,8)
#pragma unroll
  for (int i = 0; i < 4; ++i)
    tile[ty + i * 8][tx] = in[(size_t)(gy + ty + i * 8) * C + gx + tx];
  __syncthreads();
#pragma unroll
  for (int i = 0; i < 4; ++i)
    out[(size_t)(gx + ty + i * 8) * R + gy + tx] = f2bf(tile[tx][ty + i * 8]);
}

// ---------------- T5 bias table: bias[h][dist] * log2e ---------------------
__global__ __launch_bounds__(256) void bias_table(const float* __restrict__ rel_table,
                                                  float* __restrict__ btab) {
  int idx = blockIdx.x * 256 + threadIdx.x;  // 16*2048
  if (idx >= H_ * T_) return;
  int dist = idx & (T_ - 1);
  int h = idx >> 11;
  int bucket;
  if (dist < 16) {
    bucket = dist;
  } else {
    float rp = (float)dist;
    int large = 16 + (int)(logf(rp * (1.0f / 16.0f)) * (1.0f / logf(128.0f)) * 16.0f);
    bucket = large < 31 ? large : 31;
  }
  btab[idx] = rel_table[bucket * H_ + h] * LOG2E_;  // exp2-domain
}

// ---------------- bf16 GEMM: C[M,N] = A[M,K] * Bt[N,K]^T -------------------
// BM=128, BN template (128 or 64), BK=64, 4 waves, 16x16x32 MFMA,
// global_load_lds(16), XOR-swizzled LDS.
// MODE 0 (BN=128): scatter -> q(bf16, *0.125*log2e)/k(bf16)/v(bf16 LINEAR)
// MODE 1: fp32 out
template <int MODE, int BN>
__global__ __launch_bounds__(256) void gemm_bt(
    const short* __restrict__ A, const short* __restrict__ Bt,
    int M, int N, int K,
    short* __restrict__ q_out, short* __restrict__ k_out,
    short* __restrict__ v_out, float* __restrict__ f_out) {
  __shared__ alignas(16) short As[128 * 64];
  __shared__ alignas(16) short Bs[BN * 64];
  const int tid = threadIdx.x;
  const int w = tid >> 6, lane = tid & 63;
  const int g = lane >> 4, l16 = lane & 15;
  // wave tiling: BN=128 -> 2x2 waves of 64x64 (4x4 frags);
  //              BN=64  -> 4x1 waves of 32x64 (2x4 frags)
  const int wrb = (BN == 128) ? (w >> 1) * 64 : w * 32;
  const int wcb = (BN == 128) ? (w & 1) * 64 : 0;
  const int MR = (BN == 128) ? 4 : 2;
  const int m0 = blockIdx.y * 128, n0 = blockIdx.x * BN;

  const char* Ag = (const char*)(A + (size_t)m0 * K);
  const char* Bg = (const char*)(Bt + (size_t)n0 * K);
  char* AsB = (char*)As;
  char* BsB = (char*)Bs;

  // staging: A = 1024 chunks (4/thread); B = BN*8 chunks (4 or 2/thread)
  int goff[4];
#pragma unroll
  for (int i = 0; i < 4; ++i) {
    int o = i * 256 + tid;
    int row = o >> 3, ch = o & 7;
    goff[i] = row * (K * 2) + ((ch ^ (row & 7)) << 4);
  }
  const int NBI = (BN == 128) ? 4 : 2;

  f32x4 acc[MR][4] = {};

  const int nkt = K >> 6;
  for (int kt = 0; kt < nkt; ++kt) {
    __syncthreads();
    const int kbyte = kt << 7;
#pragma unroll
    for (int i = 0; i < 4; ++i)
      gload16(Ag + goff[i] + kbyte, AsB + i * 4096 + w * 1024);
#pragma unroll
    for (int i = 0; i < NBI; ++i)
      gload16(Bg + goff[i] + kbyte, BsB + i * 4096 + w * 1024);
    __syncthreads();
#pragma unroll
    for (int kk = 0; kk < 2; ++kk) {
      bf16x8 af[MR], bff[4];
#pragma unroll
      for (int m = 0; m < MR; ++m) {
        int r = wrb + m * 16 + l16;
        int off = (r * 128 + kk * 64 + g * 16) ^ ((r & 7) << 4);
        af[m] = *(const bf16x8*)(AsB + off);
      }
#pragma unroll
      for (int n = 0; n < 4; ++n) {
        int c = wcb + n * 16 + l16;
        int off = (c * 128 + kk * 64 + g * 16) ^ ((c & 7) << 4);
        bff[n] = *(const bf16x8*)(BsB + off);
      }
#pragma unroll
      for (int m = 0; m < MR; ++m)
#pragma unroll
        for (int n = 0; n < 4; ++n)
          acc[m][n] = __builtin_amdgcn_mfma_f32_16x16x32_bf16(af[m], bff[n], acc[m][n], 0, 0, 0);
    }
  }

  // epilogue: C/D layout col=lane&15, row=(lane>>4)*4+r
#pragma unroll
  for (int m = 0; m < MR; ++m) {
#pragma unroll
    for (int n = 0; n < 4; ++n) {
      const int colg = n0 + wcb + n * 16 + l16;
#pragma unroll
      for (int r = 0; r < 4; ++r) {
        const int rowg = m0 + wrb + m * 16 + g * 4 + r;
        float v = acc[m][n][r];
        if (MODE == 1) {
          f_out[(size_t)rowg * N + colg] = v;
        } else {
          int part = colg >> 10;
          int within = colg & 1023;
          int h = within >> 6, dd = within & 63;
          int b = rowg >> 11, t = rowg & (T_ - 1);
          size_t bh = (size_t)(b * H_ + h);
          if (part == 0)
            q_out[(bh * T_ + t) * D_ + dd] = f2bf(v * (0.125f * LOG2E_));  // 1/sqrt(d)*log2e
          else if (part == 1)
            k_out[(bh * T_ + t) * D_ + dd] = f2bf(v);
          else
            v_out[(bh * T_ + t) * D_ + dd] = f2bf(v);  // LINEAR (coalesced)
        }
      }
    }
  }
}

// ---------------- V transpose: [bh][t][d] -> [bh][d][t] --------------------
__global__ __launch_bounds__(256) void vtrans(const short* __restrict__ vbuf,
                                              short* __restrict__ vT) {
  __shared__ short tile[64][65];
  const int tid = threadIdx.x;
  const int bh = blockIdx.y;
  const int t0 = blockIdx.x * 64;
  const short* src = vbuf + ((size_t)bh * T_ + t0) * D_;
#pragma unroll
  for (int i = 0; i < 2; ++i) {
    int c = i * 256 + tid;
    int tr = c >> 3, dc = (c & 7) * 8;
    bf16x8 v = *(const bf16x8*)(src + tr * D_ + dc);
#pragma unroll
    for (int e = 0; e < 8; ++e) tile[tr][dc + e] = v[e];
  }
  __syncthreads();
  short* dst = vT + (size_t)bh * D_ * T_ + t0;
#pragma unroll
  for (int i = 0; i < 2; ++i) {
    int c = i * 256 + tid;
    int d = c >> 3, oct = (c & 7) * 8;
    bf16x8 o;
#pragma unroll
    for (int j = 0; j < 8; ++j) o[j] = tile[oct + j][d];
    *(bf16x8*)(dst + (size_t)d * T_ + oct) = o;
  }
}

// ---------------- flash attention with T5 bias, causal ---------------------
// KV-split work-balanced pairs (round-9 structure). exp2-domain softmax:
// q pre-scaled by 0.125*log2e, bias table *log2e, exp2f everywhere,
// defer-max THR = 8 nats = 11.54 bits. P-pack via v_cvt_pk_bf16_f32.
__global__ __launch_bounds__(256) void attn64(
    const short* __restrict__ qb, const short* __restrict__ kb,
    const short* __restrict__ vTb, const float* __restrict__ bias_tab,
    short* __restrict__ o1, short* __restrict__ o2, float* __restrict__ mlb) {
  __shared__ alignas(16) short Ks[2][64 * 64];
  __shared__ alignas(16) short Vs[64 * 64];
  __shared__ alignas(16) short Ps[4][16 * 64];
  __shared__ float biasw[2][2][128];   // [buf][lo/hi][idx]
  const int tid = threadIdx.x;
  const int w = tid >> 6, lane = tid & 63;
  const int g = lane >> 4, l16 = lane & 15;
  const int bh = blockIdx.y;          // b*16 + h
  const int h = bh & (H_ - 1);
  const int b = bh >> 4;
  const int j = blockIdx.x;           // pair index 0..15
  const int s = blockIdx.z;           // kv-split part 0/1
  const int qlo = j, qhi = 31 - j;
  const int q0l = qlo * 64, q0h = qhi * 64;

  const char* kbase = (const char*)(kb + (size_t)bh * T_ * D_);
  const char* vbase = (const char*)(vTb + (size_t)bh * D_ * T_);
  const float* btab = bias_tab + h * T_;

  bf16x8 qfl[2], qfh[2];
  {
    const short* qrl = qb + ((size_t)bh * T_ + q0l + w * 16 + l16) * D_;
    qfl[0] = *(const bf16x8*)(qrl + g * 8);
    qfl[1] = *(const bf16x8*)(qrl + 32 + g * 8);
    const short* qrh = qb + ((size_t)bh * T_ + q0h + w * 16 + l16) * D_;
    qfh[0] = *(const bf16x8*)(qrh + g * 8);
    qfh[1] = *(const bf16x8*)(qrh + 32 + g * 8);
  }

  f32x4 accl[4] = {}, acch[4] = {};
  float mlo[4], llo[4], mhi[4], lhi[4];
#pragma unroll
  for (int r = 0; r < 4; ++r) { mlo[r] = mhi[r] = -1e30f; llo[r] = lhi[r] = 0.f; }

  char* PsB = (char*)&Ps[w][0];

  int krow[2], kch[2];
#pragma unroll
  for (int i = 0; i < 2; ++i) {
    int o = i * 256 + tid;
    krow[i] = o >> 3;
    kch[i] = (o & 7) ^ (krow[i] & 7);
  }

  auto stageK = [&](int buf, int t) {
    const int kv0 = t * 64;
    char* KsB = (char*)&Ks[buf][0];
#pragma unroll
    for (int i = 0; i < 2; ++i)
      gload16(kbase + (size_t)(kv0 + krow[i]) * 128 + kch[i] * 16,
              KsB + i * 4096 + w * 1024);
  };
  auto stageV = [&](int t) {
    const int kv0 = t * 64;
    char* VsB = (char*)Vs;
#pragma unroll
    for (int i = 0; i < 2; ++i)
      gload16(vbase + (size_t)krow[i] * (T_ * 2) + kv0 * 2 + kch[i] * 16,
              VsB + i * 4096 + w * 1024);
  };
  auto biasLoad = [&](int t) -> float {
    int i = tid & 127;
    int q0x = (tid >= 128) ? q0h : q0l;
    int d = q0x - t * 64 - 63 + i;
    return (d >= 0 && d < T_) ? btab[d] : NEG_INF_;
  };

  auto computeTile = [&](const char* KsB, const float* bw, const bf16x8* qf,
                         f32x4* acc, float* mrun, float* lrun,
                         bool dosync, bool drain2) {
    // S = Q*K^T (already in log2 units via q pre-scale)
    f32x4 sreg[4];
    __builtin_amdgcn_s_setprio(1);
#pragma unroll
    for (int n = 0; n < 4; ++n) {
      int kvrow = n * 16 + l16;
      int off0 = (kvrow * 128 + g * 16) ^ ((kvrow & 7) << 4);
      int off1 = (kvrow * 128 + 64 + g * 16) ^ ((kvrow & 7) << 4);
      bf16x8 k0 = *(const bf16x8*)(KsB + off0);
      bf16x8 k1 = *(const bf16x8*)(KsB + off1);
      f32x4 z = {};
      z = __builtin_amdgcn_mfma_f32_16x16x32_bf16(qf[0], k0, z, 0, 0, 0);
      z = __builtin_amdgcn_mfma_f32_16x16x32_bf16(qf[1], k1, z, 0, 0, 0);
      sreg[n] = z;
    }
    __builtin_amdgcn_s_setprio(0);

    // bias (log2-domain) + per-row tile max
    float sv[4][4];
    float tmax[4] = {-1e30f, -1e30f, -1e30f, -1e30f};
#pragma unroll
    for (int n = 0; n < 4; ++n) {
#pragma unroll
      for (int r = 0; r < 4; ++r) {
        int idx = 63 + w * 16 + g * 4 + r - n * 16 - l16;
        float val = sreg[n][r] + bw[idx];
        sv[n][r] = val;
        tmax[r] = fmaxf(tmax[r], val);
      }
    }
#pragma unroll
    for (int r = 0; r < 4; ++r) {
      float v = tmax[r];
      v = fmaxf(v, __shfl_xor(v, 1));
      v = fmaxf(v, __shfl_xor(v, 2));
      v = fmaxf(v, __shfl_xor(v, 4));
      v = fmaxf(v, __shfl_xor(v, 8));
      tmax[r] = v;
    }

    // defer-max: skip rescale unless growth > 8 nats (11.54 bits)
    bool nogrow = true;
#pragma unroll
    for (int r = 0; r < 4; ++r) nogrow &= (tmax[r] <= mrun[r] + 11.5417f);
    if (!__all(nogrow)) {
#pragma unroll
      for (int r = 0; r < 4; ++r) {
        float mnew = fmaxf(mrun[r], tmax[r]);
        float scale = exp2f(mrun[r] - mnew);
        mrun[r] = mnew;
        lrun[r] *= scale;
#pragma unroll
        for (int dn = 0; dn < 4; ++dn) acc[dn][r] *= scale;
      }
    }

    // P = exp2(S - m); cvt_pk bf16 pack; per-lane partial l
#pragma unroll
    for (int r = 0; r < 4; ++r) {
      float su = 0.f;
      const int rowoff = (g * 4 + r) * 128;
      const int sw = ((g * 4 + r) & 7) << 4;
#pragma unroll
      for (int np = 0; np < 2; ++np) {
        float p0 = exp2f(sv[2 * np][r] - mrun[r]);
        float p1 = exp2f(sv[2 * np + 1][r] - mrun[r]);
        su += p0 + p1;
        unsigned pk;
        asm("v_cvt_pk_bf16_f32 %0, %1, %2" : "=v"(pk) : "v"(p0), "v"(p1));
        *(short*)(PsB + ((rowoff + (2 * np * 16 + l16) * 2) ^ sw)) = (short)pk;
        *(short*)(PsB + ((rowoff + ((2 * np + 1) * 16 + l16) * 2) ^ sw)) = (short)(pk >> 16);
      }
      lrun[r] += su;
    }

    // V-ready sync (first compute of the iteration only)
    if (dosync) {
      if (drain2) {
        asm volatile("s_waitcnt vmcnt(2)" ::: "memory");
      } else {
        asm volatile("s_waitcnt vmcnt(0)" ::: "memory");
      }
      __builtin_amdgcn_s_barrier();
      __builtin_amdgcn_sched_barrier(0);
    }

    // O += P*V
    const char* VsB = (const char*)Vs;
    bf16x8 pf[2];
    {
      int o0 = (l16 * 128 + g * 16) ^ ((l16 & 7) << 4);
      int o1 = (l16 * 128 + 64 + g * 16) ^ ((l16 & 7) << 4);
      pf[0] = *(const bf16x8*)(PsB + o0);
      pf[1] = *(const bf16x8*)(PsB + o1);
    }
    __builtin_amdgcn_s_setprio(1);
#pragma unroll
    for (int dn = 0; dn < 4; ++dn) {
      int drow = dn * 16 + l16;
      int o0 = (drow * 128 + g * 16) ^ ((drow & 7) << 4);
      int o1 = (drow * 128 + 64 + g * 16) ^ ((drow & 7) << 4);
      bf16x8 v0 = *(const bf16x8*)(VsB + o0);
      bf16x8 v1 = *(const bf16x8*)(VsB + o1);
      acc[dn] = __builtin_amdgcn_mfma_f32_16x16x32_bf16(pf[0], v0, acc[dn], 0, 0, 0);
      acc[dn] = __builtin_amdgcn_mfma_f32_16x16x32_bf16(pf[1], v1, acc[dn], 0, 0, 0);
    }
    __builtin_amdgcn_s_setprio(0);
  };

  // prologue
  stageK(0, s);
  {
    float bv = biasLoad(s);
    biasw[0][tid >> 7][tid & 127] = bv;
  }
  __syncthreads();

  int cur = 0;
  for (int t = s; t <= qhi; t += 2) {
    const int nxt = cur ^ 1;
    const bool hasnext = (t + 2 <= qhi);
    float bvn = 0.f;
    if (hasnext) bvn = biasLoad(t + 2);  // VMEM load issued first (oldest)
    stageV(t);                           // V of current tile (single buffer)
    if (hasnext) stageK(nxt, t + 2);     // K prefetch (newest 2 loads)
    const char* KsB = (const char*)&Ks[cur][0];
    bool first = true;
    if (t <= qlo) {
      computeTile(KsB, &biasw[cur][0][0], qfl, accl, mlo, llo, true, hasnext);
      first = false;
    }
    computeTile(KsB, &biasw[cur][1][0], qfh, acch, mhi, lhi, first, hasnext);
    if (hasnext) biasw[nxt][tid >> 7][tid & 127] = bvn;
    __syncthreads();
    cur = nxt;
  }

  // epilogue: reduce l across l16; write UNNORMALIZED O + per-row (m,l)
  short* dst = (s == 0) ? o1 : o2;
  auto writeO = [&](int q0x, const f32x4* acc, const float* mrun, float* lrun) {
#pragma unroll
    for (int r = 0; r < 4; ++r) {
      float v = lrun[r];
      v += __shfl_xor(v, 1);
      v += __shfl_xor(v, 2);
      v += __shfl_xor(v, 4);
      v += __shfl_xor(v, 8);
      int qg = q0x + w * 16 + g * 4 + r;
      size_t ybase = ((size_t)b * T_ + qg) * C_ + h * D_;
#pragma unroll
      for (int dn = 0; dn < 4; ++dn)
        dst[ybase + dn * 16 + l16] = f2bf(acc[dn][r]);
      if (l16 == 0) {
        int idx = (((b * T_) + qg) * H_ + h) * 4 + s * 2;
        mlb[idx] = mrun[r];     // log2-domain
        mlb[idx + 1] = v;
      }
    }
  };
  writeO(q0l, accl, mlo, llo);
  writeO(q0h, acch, mhi, lhi);
}

// ---------------- merge the two kv-split partials (log2-domain m) ----------
__global__ __launch_bounds__(256) void attn_merge(
    short* __restrict__ o1, const short* __restrict__ o2,
    const float* __restrict__ mlb) {
  int i = blockIdx.x * 256 + threadIdx.x;   // 524288 total
  int row = i >> 7;                          // b*T + t
  int h = (i & 127) >> 3;
  float4 q = ((const float4*)mlb)[row * H_ + h];  // (m0,l0,m1,l1)
  float m = fmaxf(q.x, q.z);
  float w0 = exp2f(q.x - m), w1 = exp2f(q.z - m);
  float inv = 1.0f / (w0 * q.y + w1 * q.w);
  bf16x8 a = ((const bf16x8*)o1)[i];
  bf16x8 bb = ((const bf16x8*)o2)[i];
  bf16x8 o;
#pragma unroll
  for (int e = 0; e < 8; ++e)
    o[e] = f2bf((w0 * bf2f(a[e]) + w1 * bf2f(bb[e])) * inv);
  ((bf16x8*)o1)[i] = o;
}

// ---------------------------------------------------------------------------
extern "C" void kernel_launch(void* const* d_in, const int* in_sizes, int n_in,
                              void* d_out, int out_size, void* d_ws, size_t ws_size,
                              hipStream_t stream) {
  const float* x = (const float*)d_in[0];         // [2,2048,1024]
  const float* w_qkv = (const float*)d_in[1];     // [1024,3072]
  const float* w_proj = (const float*)d_in[2];    // [1024,1024]
  const float* rel_table = (const float*)d_in[3]; // [32,16]
  float* out = (float*)d_out;                     // [2,2048,1024]

  const size_t MB = 1024 * 1024;
  char* ws = (char*)d_ws;
  short* xb     = (short*)(ws);             // 0-8 MB   x bf16 (dead after gemm1)
  short* wqkvT  = (short*)(ws + 8 * MB);    // 8-14 MB  (dead after gemm1)
  short* wprojT = (short*)(ws + 14 * MB);   // 14-16 MB (live till gemm2)
  short* qb     = (short*)(ws + 16 * MB);   // 16-24 MB [B,H,T,64] (pre-scaled)
  short* kbuf   = (short*)(ws + 24 * MB);   // 24-32 MB [B,H,T,64]
  short* vbuf   = (short*)(ws + 32 * MB);   // 32-40 MB [B,H,T,64] linear (dead after vtrans)
  short* vT     = (short*)(ws + 40 * MB);   // 40-48 MB [B,H,64,T]
  float* btab   = (float*)(ws + 48 * MB);   // 48 MB + 128 KB
  // overlays of dead regions:
  short* o2b    = (short*)(ws);             // 0-8 MB   attn part-1 O (over xb)
  float* mlb    = (float*)(ws + 9 * MB);    // 9-10 MB  (over wqkvT)
  short* o1b    = (short*)(ws + 32 * MB);   // 32-40 MB attn part-0 O / merged y (over vbuf)

  // 1. conversions
  cvt_bf16<<<4096, 256, 0, stream>>>(x, xb, (B_ * T_ * C_) / 4);
  dim3 tb(32, 8);
  transpose_cvt<<<dim3(96, 32), tb, 0, stream>>>(w_qkv, wqkvT, 1024, 3072);
  transpose_cvt<<<dim3(32, 32), tb, 0, stream>>>(w_proj, wprojT, 1024, 1024);
  bias_table<<<128, 256, 0, stream>>>(rel_table, btab);

  // 2. qkv = x @ w_qkv  (scatter to q/k/v-linear)
  gemm_bt<0, 128><<<dim3(24, 32), 256, 0, stream>>>(xb, wqkvT, 4096, 3072, 1024,
                                                    qb, kbuf, vbuf, nullptr);
  // 2b. transpose V
  vtrans<<<dim3(32, 32), 256, 0, stream>>>(vbuf, vT);

  // 3. attention (work-balanced pairs x kv-split) + merge
  attn64<<<dim3(16, 32, 2), 256, 0, stream>>>(qb, kbuf, vT, btab, o1b, o2b, mlb);
  attn_merge<<<2048, 256, 0, stream>>>(o1b, o2b, mlb);

  // 4. out = y @ w_proj  (BN=64 -> 512 blocks, 2/CU)
  gemm_bt<1, 64><<<dim3(16, 32), 256, 0, stream>>>(o1b, wprojT, 4096, 1024, 1024,
                                                   nullptr, nullptr, nullptr, out);
}